// Round 18
// baseline (214.631 us; speedup 1.0000x reference)
//
#include <hip/hip_runtime.h>
#include <math.h>

#define NVOX 50000
#define PPTS 32
#define HDIM 64
#define ODIM 128
#define EPSBN 1e-5f

typedef _Float16 f16x8 __attribute__((ext_vector_type(8)));
typedef _Float16 f16x4 __attribute__((ext_vector_type(4)));
typedef float f32x4 __attribute__((ext_vector_type(4)));

// d_ws layout (f16 elements unless noted):
//   [0, 512)       W1c: 64 rows x 8 f16  {w0..w3, c1, 0,0,0}   (BN-folded layer1)
//                  rows PERMUTED by perm(p) so phase-1 D output packs directly
//                  into phase-2 B fragments (in-register chaining, no LDS).
//   [512, 4608)    W2T: [row_phys][ch_in] 64x64, BN-folded; rows permuted by perm(p),
//                  columns natural (phase-1 pack delivers slot k = natural channel).
//   [4608, 12800)  W3T: [o][ch_in] 128x64 natural (phase-2 pack is identity too)
//   byte 25600:    f32 c2[64] natural, f32 b3[128]
#define WS_W1C 0
#define WS_W2T 512
#define WS_W3T 4608
#define WS_F32_BYTE 25600
#define FOLD_THREADS 12992

// Structure history (PROVEN on this problem):
//  - one chunk (64 pts / 2 voxels) per wave; all multi-chunk forms leak to
//    scratch (r5/7/12). Wave-uniform 16-pt group skip: bit-exact +10% (r8).
//  - VALU cut (pk_max_f16 relu + max3 trees): kept since r15.
//  - 128-thread blocks beat 256 by 11% (r17: 64.6 us, VGPR 64, Occ ~36%).
//  - r14: W3 loads INSIDE phase 3 from L2 = +25 us (exposed latency).
//  - r16: write-late LDS staging = post-timing race. Both dead ends.
//  - THIS ROUND: per-lane W3 PRELOAD INTO REGISTERS at kernel top (before
//    phases 1+2, which hide the L2 latency). Zero LDS, zero barrier, zero
//    shared state -> r16's race class is impossible; unlike r14 the loads
//    are off the phase-3 critical path. +64 VGPR (16x f16x8, statically
//    indexed, unconditional = demotion-safe form). launch_bounds(128,3):
//    cap 170, the only never-spilled cap (85 and tight-128 both misbehaved).

// Row permutation: physical MFMA-A row p (tile mt = p>>4, mu = p&15) holds
// logical channel 32*(mt&1) + 8*(mu>>2) + 4*(mt>>1) + (mu&3).
// Then lane(q,m16)'s D regs acc[mt][r] hold channels 32*(mt&1)+8q+4*(mt>>1)+r,
// and packing frag[kk=mt&1][j=4*(mt>>1)+r] puts channel c in B/A slot k = c.
__device__ __host__ inline int permch(int p) {
    return ((p >> 4) & 1) * 32 + ((p >> 2) & 3) * 8 + ((p >> 5) & 1) * 4 + (p & 3);
}

__global__ void vfe_fold(
    const float* __restrict__ W1, const float* __restrict__ b1,
    const float* __restrict__ g1, const float* __restrict__ be1,
    const float* __restrict__ m1, const float* __restrict__ v1,
    const float* __restrict__ W2, const float* __restrict__ b2,
    const float* __restrict__ g2, const float* __restrict__ be2,
    const float* __restrict__ m2, const float* __restrict__ v2,
    const float* __restrict__ W3, const float* __restrict__ b3,
    _Float16* __restrict__ wsh, float* __restrict__ wsf)
{
    int t = blockIdx.x * 256 + threadIdx.x;
    if (t < 512) {                               // W1c, rows permuted
        int p = t >> 3, i = t & 7;
        int ch = permch(p);
        float s1 = g1[ch] * rsqrtf(v1[ch] + EPSBN);
        float val;
        if (i < 4)      val = W1[i * 64 + ch] * s1;
        else if (i == 4) val = (b1[ch] - m1[ch]) * s1 + be1[ch];
        else             val = 0.f;
        wsh[WS_W1C + t] = (_Float16)val;
    } else if (t < 4608) {                       // W2T folded: rows permuted, cols natural
        int e = t - 512;
        int p = e >> 6, ch = e & 63;
        int chp = permch(p);
        float s2 = g2[chp] * rsqrtf(v2[chp] + EPSBN);
        wsh[t] = (_Float16)(W2[ch * 64 + chp] * s2);
    } else if (t < 12800) {                      // W3T: [o][ch] natural
        int e = t - 4608;
        int o = e >> 6, ch = e & 63;
        wsh[t] = (_Float16)W3[ch * 128 + o];
    } else if (t < 12864) {                      // c2 natural (indexing handled in mfma)
        int i = t - 12800;
        float s2 = g2[i] * rsqrtf(v2[i] + EPSBN);
        wsf[i] = (b2[i] - m2[i]) * s2 + be2[i];
    } else if (t < FOLD_THREADS) {               // b3
        int i = t - 12864;
        wsf[64 + i] = b3[i];
    }
}

// launch_bounds(128,3): VGPR cap 170 — the only cap that has never spilled
// this codegen (85 and tight-128 both misbehaved). LDS = 0; 2-wave blocks,
// no barrier, waves fully independent.
__global__ __launch_bounds__(128, 3) void vfe_mfma(
    const float* __restrict__ vf, const int* __restrict__ vnp,
    const _Float16* __restrict__ wsh, const float* __restrict__ wsf,
    float* __restrict__ out)
{
    const int tid  = threadIdx.x;                // 0..127 (2 waves)
    const int wave = tid >> 6;
    const int lane = tid & 63;
    const int q    = lane >> 4;
    const int m16  = lane & 15;

    const int wavebase = blockIdx.x * 128 + wave * 64;  // 64 points = 2 voxels
    const int voxA = wavebase >> 5;

    // ---- per-lane W3 fragment preload into REGISTERS, issued first ----
    // w3r[2*nt] / w3r[2*nt+1] = phase-3 b30/b31 for row o = nt*16+m16:
    // granule q (bytes [q*16,q*16+16)) and granule 4+q. 16 x f16x8 = 64 VGPR.
    // All 16 loads in flight while phases 1+2 compute -> latency hidden.
    f16x8 w3r[16];
#pragma unroll
    for (int nt = 0; nt < 8; ++nt) {
        const int o = nt * 16 + m16;
        w3r[2 * nt]     = *(const f16x8*)&wsh[WS_W3T + o * 64 + q * 8];
        w3r[2 * nt + 1] = *(const f16x8*)&wsh[WS_W3T + o * 64 + 32 + q * 8];
    }

    // ---- wave-uniform / per-lane global preloads ----
    const int nA = vnp[voxA];
    const int nB = vnp[voxA + 1];
    const bool actB1 = (nA > 16);    // g=1 (voxA points 16..31) has any valid point
    const bool actB3 = (nB > 16);    // g=3 (voxB points 16..31) has any valid point

    f16x8 a1[4];
#pragma unroll
    for (int mt = 0; mt < 4; ++mt) {
        f16x8 t = *(const f16x8*)&wsh[WS_W1C + (m16 + 16 * mt) * 8];
        a1[mt] = (q == 0) ? t : (f16x8)0;      // k = q*8+j; only k<8 carries data
    }
    f16x8 a2[4][2];
#pragma unroll
    for (int mt = 0; mt < 4; ++mt)
#pragma unroll
        for (int kk = 0; kk < 2; ++kk)
            a2[mt][kk] = *(const f16x8*)&wsh[WS_W2T + (m16 + 16 * mt) * 64 + kk * 32 + q * 8];
    // c2 init must follow the permuted D2 rows: acc[mt][r] is out-channel
    // 32*(mt&1) + 8q + 4*(mt>>1) + r  (contiguous in r -> vector load).
    f32x4 c2v[4];
#pragma unroll
    for (int mt = 0; mt < 4; ++mt)
        c2v[mt] = *(const f32x4*)(wsf + (mt & 1) * 32 + q * 8 + (mt >> 1) * 4);

    // input points: only q==0 lanes feed the phase-1 B fragment
    float4 xv[4];
#pragma unroll
    for (int g = 0; g < 4; ++g)
        if (q == 0)
            xv[g] = *(const float4*)(vf + ((size_t)wavebase + g * 16 + m16) * 4);

    // ======== PHASES 1+2 fused, fully in-register ========
    // a3 zero-initialized so skipped groups stay fully defined (no
    // conditionally-undef registers -> no demotion hazard).
    f16x8 a3[4][2] = {};
#pragma unroll
    for (int g = 0; g < 4; ++g) {
        if (g == 1 && !actB1) continue;          // wave-uniform skip (bit-exact)
        if (g == 3 && !actB3) continue;
        f16x8 b = (f16x8)0;
        if (q == 0) {
            b[0] = (_Float16)xv[g].x; b[1] = (_Float16)xv[g].y;
            b[2] = (_Float16)xv[g].z; b[3] = (_Float16)xv[g].w;
            b[4] = (_Float16)1.0f;               // homogeneous slot carries c1
        }
        // layer 1: 4 independent MFMAs (tiles mt)
        f32x4 p1[4];
#pragma unroll
        for (int mt = 0; mt < 4; ++mt) {
            f32x4 z = {0.f, 0.f, 0.f, 0.f};
            p1[mt] = __builtin_amdgcn_mfma_f32_16x16x32_f16(a1[mt], b, z, 0, 0, 0);
        }
        // convert (RTN, unchanged numerics) then PACKED relu: 4 v_pk_max_f16
        // replace 16 v_max_f32. relu∘cvt == cvt∘relu for all inputs.
        f16x8 b20, b21;
#pragma unroll
        for (int r = 0; r < 4; ++r) {
            b20[r]     = (_Float16)p1[0][r];
            b20[4 + r] = (_Float16)p1[2][r];
            b21[r]     = (_Float16)p1[1][r];
            b21[4 + r] = (_Float16)p1[3][r];
        }
        b20 = __builtin_elementwise_max(b20, (f16x8)0);
        b21 = __builtin_elementwise_max(b21, (f16x8)0);
        // layer 2
        f32x4 p2[4];
#pragma unroll
        for (int mt = 0; mt < 4; ++mt) {
            f32x4 acc = c2v[mt];
            acc = __builtin_amdgcn_mfma_f32_16x16x32_f16(a2[mt][0], b20, acc, 0, 0, 0);
            acc = __builtin_amdgcn_mfma_f32_16x16x32_f16(a2[mt][1], b21, acc, 0, 0, 0);
            p2[mt] = acc;
        }
        // convert + packed relu into phase-3 A fragments (same identity map)
        f16x8 h0, h1;
#pragma unroll
        for (int r = 0; r < 4; ++r) {
            h0[r]     = (_Float16)p2[0][r];
            h0[4 + r] = (_Float16)p2[2][r];
            h1[r]     = (_Float16)p2[1][r];
            h1[4 + r] = (_Float16)p2[3][r];
        }
        a3[g][0] = __builtin_elementwise_max(h0, (f16x8)0);
        a3[g][1] = __builtin_elementwise_max(h1, (f16x8)0);
    }

    // ======== PHASE 3: layer 3, nt-outer / g-inner, W3 from REGISTERS ========
    f32x4 macc4[4];
#pragma unroll
    for (int g = 0; g < 4; ++g) {
        const int n = (g < 2) ? nA : nB;
        const int slotbase = (g & 1) * 16 + q * 4;
#pragma unroll
        for (int r = 0; r < 4; ++r)
            macc4[g][r] = (slotbase + r < n) ? 0.f : -INFINITY;
    }

    float vmA[8], vmB[8];
#pragma unroll
    for (int nt = 0; nt < 8; ++nt) { vmA[nt] = -INFINITY; vmB[nt] = -INFINITY; }

#pragma unroll
    for (int nt = 0; nt < 8; ++nt) {
        const f16x8 b30 = w3r[2 * nt];
        const f16x8 b31 = w3r[2 * nt + 1];
#pragma unroll
        for (int g = 0; g < 4; ++g) {
            if (g == 1 && !actB1) continue;      // skipped group stays -INF
            if (g == 3 && !actB3) continue;
            f32x4 acc = macc4[g];
            acc = __builtin_amdgcn_mfma_f32_16x16x32_f16(a3[g][0], b30, acc, 0, 0, 0);
            acc = __builtin_amdgcn_mfma_f32_16x16x32_f16(a3[g][1], b31, acc, 0, 0, 0);
            // max3-shaped: fmaxf(fmaxf(x,y),z) fuses to v_max3_f32 -> 2 ops
            float t = fmaxf(fmaxf(acc[0], acc[1]), acc[2]);
            if (g < 2) vmA[nt] = fmaxf(fmaxf(vmA[nt], t), acc[3]);
            else       vmB[nt] = fmaxf(fmaxf(vmB[nt], t), acc[3]);
        }
    }

    // ======== epilogue: cross-quad max, bias, store (2 voxels) ========
    float b3r[8];                                // loaded late to cut reg pressure
#pragma unroll
    for (int nt = 0; nt < 8; ++nt) b3r[nt] = wsf[64 + nt * 16 + m16];

#pragma unroll
    for (int nt = 0; nt < 8; ++nt) {
        float t0 = vmA[nt];
        t0 = fmaxf(t0, __shfl_xor(t0, 16));
        t0 = fmaxf(t0, __shfl_xor(t0, 32));
        float t1 = vmB[nt];
        t1 = fmaxf(t1, __shfl_xor(t1, 16));
        t1 = fmaxf(t1, __shfl_xor(t1, 32));
        if (q == 0) out[(size_t)(voxA + 0) * ODIM + nt * 16 + m16] = t0 + b3r[nt];
        if (q == 1) out[(size_t)(voxA + 1) * ODIM + nt * 16 + m16] = t1 + b3r[nt];
    }
}

extern "C" void kernel_launch(void* const* d_in, const int* in_sizes, int n_in,
                              void* d_out, int out_size, void* d_ws, size_t ws_size,
                              hipStream_t stream) {
    const float* vf  = (const float*)d_in[0];
    const int*   vnp = (const int*)d_in[1];
    const float* W1  = (const float*)d_in[2];
    const float* b1  = (const float*)d_in[3];
    const float* g1  = (const float*)d_in[4];
    const float* be1 = (const float*)d_in[5];
    const float* m1  = (const float*)d_in[6];
    const float* v1  = (const float*)d_in[7];
    const float* W2  = (const float*)d_in[8];
    const float* b2  = (const float*)d_in[9];
    const float* g2  = (const float*)d_in[10];
    const float* be2 = (const float*)d_in[11];
    const float* m2  = (const float*)d_in[12];
    const float* v2  = (const float*)d_in[13];
    const float* W3  = (const float*)d_in[14];
    const float* b3  = (const float*)d_in[15];
    float* out = (float*)d_out;

    _Float16* wsh = (_Float16*)d_ws;
    float*    wsf = (float*)((char*)d_ws + WS_F32_BYTE);

    vfe_fold<<<(FOLD_THREADS + 255) / 256, 256, 0, stream>>>(
        W1, b1, g1, be1, m1, v1, W2, b2, g2, be2, m2, v2, W3, b3, wsh, wsf);

    const int blocks = (NVOX * PPTS) / 128;   // 12500
    vfe_mfma<<<blocks, 128, 0, stream>>>(vf, vnp, wsh, wsf, out);
}

// Round 20
// 148.861 us; speedup vs baseline: 1.4418x; 1.4418x over previous
//
#include <hip/hip_runtime.h>
#include <math.h>

#define NVOX 50000
#define PPTS 32
#define HDIM 64
#define ODIM 128
#define EPSBN 1e-5f

typedef _Float16 f16x8 __attribute__((ext_vector_type(8)));
typedef _Float16 f16x4 __attribute__((ext_vector_type(4)));
typedef float f32x4 __attribute__((ext_vector_type(4)));

// d_ws layout (f16 elements unless noted):
//   [0, 512)       W1c: 64 rows x 8 f16  {w0..w3, c1, 0,0,0}   (BN-folded layer1)
//                  rows PERMUTED by perm(p) so phase-1 D output packs directly
//                  into phase-2 B fragments (in-register chaining, no LDS).
//   [512, 4608)    W2T: [row_phys][ch_in] 64x64, BN-folded; rows permuted by perm(p),
//                  columns natural (phase-1 pack delivers slot k = natural channel).
//   [4608, 12800)  W3T: [o][granule] 128x64, PRE-SWIZZLED: granule ph = gl^(o&7)
//                  stored at [o*64 + ph*8] so vfe_mfma's staging is a linear copy.
//   byte 25600:    f32 c2[64] natural, f32 b3[128]
#define WS_W1C 0
#define WS_W2T 512
#define WS_W3T 4608
#define WS_F32_BYTE 25600
#define FOLD_THREADS 12992

// Structure history (PROVEN on this problem):
//  - one chunk (64 pts / 2 voxels) per wave; all multi-chunk forms leak to
//    scratch (r5/7/12). Wave-uniform 16-pt group skip: bit-exact +10% (r8).
//  - VALU cut (pk_max_f16 relu + max3 trees): kept since r15.
//  - 128-thread blocks beat 256 by 11% (r17: 64.6 us, VGPR 64).
//  - W3 residency: LDS tile (r17) > direct-L2 in phase 3 (r14, +25us) >
//    per-lane reg preload (r18: 16xf16x8 spilled, WRITE 25->129 MB). CLOSED.
//  - r16 write-late staging: post-timing race. Barrier stays before phase 1.
//  - THIS ROUND (issue-order only, zero new state): vf/vnp HBM loads issued
//    FIRST (their ~900cyc latency was exposed at the top of phase 1 when
//    issued last); W3 staging moved LAST before the unmoved barrier (its
//    data isn't consumed until phase 3). Fold pre-swizzles W3T so staging
//    is a linear copy (XOR VALU removed from the hot kernel).

// Row permutation: physical MFMA-A row p (tile mt = p>>4, mu = p&15) holds
// logical channel 32*(mt&1) + 8*(mu>>2) + 4*(mt>>1) + (mu&3).
// Then lane(q,m16)'s D regs acc[mt][r] hold channels 32*(mt&1)+8q+4*(mt>>1)+r,
// and packing frag[kk=mt&1][j=4*(mt>>1)+r] puts channel c in B/A slot k = c.
__device__ __host__ inline int permch(int p) {
    return ((p >> 4) & 1) * 32 + ((p >> 2) & 3) * 8 + ((p >> 5) & 1) * 4 + (p & 3);
}

__global__ void vfe_fold(
    const float* __restrict__ W1, const float* __restrict__ b1,
    const float* __restrict__ g1, const float* __restrict__ be1,
    const float* __restrict__ m1, const float* __restrict__ v1,
    const float* __restrict__ W2, const float* __restrict__ b2,
    const float* __restrict__ g2, const float* __restrict__ be2,
    const float* __restrict__ m2, const float* __restrict__ v2,
    const float* __restrict__ W3, const float* __restrict__ b3,
    _Float16* __restrict__ wsh, float* __restrict__ wsf)
{
    int t = blockIdx.x * 256 + threadIdx.x;
    if (t < 512) {                               // W1c, rows permuted
        int p = t >> 3, i = t & 7;
        int ch = permch(p);
        float s1 = g1[ch] * rsqrtf(v1[ch] + EPSBN);
        float val;
        if (i < 4)      val = W1[i * 64 + ch] * s1;
        else if (i == 4) val = (b1[ch] - m1[ch]) * s1 + be1[ch];
        else             val = 0.f;
        wsh[WS_W1C + t] = (_Float16)val;
    } else if (t < 4608) {                       // W2T folded: rows permuted, cols natural
        int e = t - 512;
        int p = e >> 6, ch = e & 63;
        int chp = permch(p);
        float s2 = g2[chp] * rsqrtf(v2[chp] + EPSBN);
        wsh[t] = (_Float16)(W2[ch * 64 + chp] * s2);
    } else if (t < 12800) {                      // W3T: [o][ch], PRE-SWIZZLED granules
        int e = t - 4608;
        int o = e >> 6, ch = e & 63;             // logical element
        int gl = ch >> 3, j = ch & 7;            // logical granule, elem in granule
        int ph = gl ^ (o & 7);                   // physical granule (XOR swizzle)
        wsh[WS_W3T + o * 64 + ph * 8 + j] = (_Float16)W3[ch * 128 + o];
    } else if (t < 12864) {                      // c2 natural (indexing handled in mfma)
        int i = t - 12800;
        float s2 = g2[i] * rsqrtf(v2[i] + EPSBN);
        wsf[i] = (b2[i] - m2[i]) * s2 + be2[i];
    } else if (t < FOLD_THREADS) {               // b3
        int i = t - 12864;
        wsf[64 + i] = b3[i];
    }
}

// launch_bounds(128,4): VGPR cap 128 (verified no-spill for this 64-VGPR
// body at r17); 2-wave blocks, one barrier.
__global__ __launch_bounds__(128, 4) void vfe_mfma(
    const float* __restrict__ vf, const int* __restrict__ vnp,
    const _Float16* __restrict__ wsh, const float* __restrict__ wsf,
    float* __restrict__ out)
{
    // Block-shared W3 tile, stored pre-swizzled (fold applied the XOR), so
    // staging is a LINEAR copy and phase-3 reads use the same XOR addressing
    // as r17 (2-way conflicts = free).
    __shared__ __align__(16) _Float16 sW3[ODIM * HDIM];    // 16384 B

    const int tid  = threadIdx.x;                // 0..127 (2 waves)
    const int wave = tid >> 6;
    const int lane = tid & 63;
    const int q    = lane >> 4;
    const int m16  = lane & 15;

    const int wavebase = blockIdx.x * 128 + wave * 64;  // 64 points = 2 voxels
    const int voxA = wavebase >> 5;

    // ---- 1) HBM loads FIRST: vnp + points (longest latency, needed first) ----
    const int nA = vnp[voxA];
    const int nB = vnp[voxA + 1];

    float4 xv[4];
#pragma unroll
    for (int g = 0; g < 4; ++g)
        if (q == 0)
            xv[g] = *(const float4*)(vf + ((size_t)wavebase + g * 16 + m16) * 4);

    const bool actB1 = (nA > 16);    // g=1 (voxA points 16..31) has any valid point
    const bool actB3 = (nB > 16);    // g=3 (voxB points 16..31) has any valid point

    // ---- 2) weight preloads (L2-hot) ----
    f16x8 a1[4];
#pragma unroll
    for (int mt = 0; mt < 4; ++mt) {
        f16x8 t = *(const f16x8*)&wsh[WS_W1C + (m16 + 16 * mt) * 8];
        a1[mt] = (q == 0) ? t : (f16x8)0;      // k = q*8+j; only k<8 carries data
    }
    f16x8 a2[4][2];
#pragma unroll
    for (int mt = 0; mt < 4; ++mt)
#pragma unroll
        for (int kk = 0; kk < 2; ++kk)
            a2[mt][kk] = *(const f16x8*)&wsh[WS_W2T + (m16 + 16 * mt) * 64 + kk * 32 + q * 8];
    // c2 init must follow the permuted D2 rows: acc[mt][r] is out-channel
    // 32*(mt&1) + 8q + 4*(mt>>1) + r  (contiguous in r -> vector load).
    f32x4 c2v[4];
#pragma unroll
    for (int mt = 0; mt < 4; ++mt)
        c2v[mt] = *(const f32x4*)(wsf + (mt & 1) * 32 + q * 8 + (mt >> 1) * 4);

    // ---- 3) W3 staging LAST before barrier (consumed only in phase 3):
    //         linear copy, source pre-swizzled by fold ----
#pragma unroll
    for (int i = 0; i < 8; ++i) {
        int e = tid + 128 * i;                   // f16x8 granule id, 0..1023
        f16x8 v = *(const f16x8*)&wsh[WS_W3T + e * 8];
        *(f16x8*)&sW3[e * 8] = v;
    }

    __syncthreads();                             // W3 tile ready (only barrier)

    // ======== PHASES 1+2 fused, fully in-register (no activation LDS) ========
    // a3 zero-initialized so skipped groups stay fully defined (no
    // conditionally-undef registers -> no demotion hazard).
    f16x8 a3[4][2] = {};
#pragma unroll
    for (int g = 0; g < 4; ++g) {
        if (g == 1 && !actB1) continue;          // wave-uniform skip (bit-exact)
        if (g == 3 && !actB3) continue;
        f16x8 b = (f16x8)0;
        if (q == 0) {
            b[0] = (_Float16)xv[g].x; b[1] = (_Float16)xv[g].y;
            b[2] = (_Float16)xv[g].z; b[3] = (_Float16)xv[g].w;
            b[4] = (_Float16)1.0f;               // homogeneous slot carries c1
        }
        // layer 1: 4 independent MFMAs (tiles mt)
        f32x4 p1[4];
#pragma unroll
        for (int mt = 0; mt < 4; ++mt) {
            f32x4 z = {0.f, 0.f, 0.f, 0.f};
            p1[mt] = __builtin_amdgcn_mfma_f32_16x16x32_f16(a1[mt], b, z, 0, 0, 0);
        }
        // convert (RTN, unchanged numerics) then PACKED relu: 4 v_pk_max_f16
        // replace 16 v_max_f32. relu∘cvt == cvt∘relu for all inputs.
        f16x8 b20, b21;
#pragma unroll
        for (int r = 0; r < 4; ++r) {
            b20[r]     = (_Float16)p1[0][r];
            b20[4 + r] = (_Float16)p1[2][r];
            b21[r]     = (_Float16)p1[1][r];
            b21[4 + r] = (_Float16)p1[3][r];
        }
        b20 = __builtin_elementwise_max(b20, (f16x8)0);
        b21 = __builtin_elementwise_max(b21, (f16x8)0);
        // layer 2
        f32x4 p2[4];
#pragma unroll
        for (int mt = 0; mt < 4; ++mt) {
            f32x4 acc = c2v[mt];
            acc = __builtin_amdgcn_mfma_f32_16x16x32_f16(a2[mt][0], b20, acc, 0, 0, 0);
            acc = __builtin_amdgcn_mfma_f32_16x16x32_f16(a2[mt][1], b21, acc, 0, 0, 0);
            p2[mt] = acc;
        }
        // convert + packed relu into phase-3 A fragments (same identity map)
        f16x8 h0, h1;
#pragma unroll
        for (int r = 0; r < 4; ++r) {
            h0[r]     = (_Float16)p2[0][r];
            h0[4 + r] = (_Float16)p2[2][r];
            h1[r]     = (_Float16)p2[1][r];
            h1[4 + r] = (_Float16)p2[3][r];
        }
        a3[g][0] = __builtin_elementwise_max(h0, (f16x8)0);
        a3[g][1] = __builtin_elementwise_max(h1, (f16x8)0);
    }

    // ======== PHASE 3: layer 3, nt-outer / g-inner, W3 frags from LDS ========
    f32x4 macc4[4];
#pragma unroll
    for (int g = 0; g < 4; ++g) {
        const int n = (g < 2) ? nA : nB;
        const int slotbase = (g & 1) * 16 + q * 4;
#pragma unroll
        for (int r = 0; r < 4; ++r)
            macc4[g][r] = (slotbase + r < n) ? 0.f : -INFINITY;
    }

    float vmA[8], vmB[8];
#pragma unroll
    for (int nt = 0; nt < 8; ++nt) { vmA[nt] = -INFINITY; vmB[nt] = -INFINITY; }

#pragma unroll
    for (int nt = 0; nt < 8; ++nt) {
        const int o = nt * 16 + m16;
        f16x8 b30 = *(const f16x8*)&sW3[o * 64 + ((q    ) ^ (m16 & 7)) * 8];
        f16x8 b31 = *(const f16x8*)&sW3[o * 64 + ((4 + q) ^ (m16 & 7)) * 8];
#pragma unroll
        for (int g = 0; g < 4; ++g) {
            if (g == 1 && !actB1) continue;      // skipped group stays -INF
            if (g == 3 && !actB3) continue;
            f32x4 acc = macc4[g];
            acc = __builtin_amdgcn_mfma_f32_16x16x32_f16(a3[g][0], b30, acc, 0, 0, 0);
            acc = __builtin_amdgcn_mfma_f32_16x16x32_f16(a3[g][1], b31, acc, 0, 0, 0);
            // max3-shaped: fmaxf(fmaxf(x,y),z) fuses to v_max3_f32 -> 2 ops
            float t = fmaxf(fmaxf(acc[0], acc[1]), acc[2]);
            if (g < 2) vmA[nt] = fmaxf(fmaxf(vmA[nt], t), acc[3]);
            else       vmB[nt] = fmaxf(fmaxf(vmB[nt], t), acc[3]);
        }
    }

    // ======== epilogue: cross-quad max, bias, store (2 voxels) ========
    float b3r[8];                                // loaded late to cut reg pressure
#pragma unroll
    for (int nt = 0; nt < 8; ++nt) b3r[nt] = wsf[64 + nt * 16 + m16];

#pragma unroll
    for (int nt = 0; nt < 8; ++nt) {
        float t0 = vmA[nt];
        t0 = fmaxf(t0, __shfl_xor(t0, 16));
        t0 = fmaxf(t0, __shfl_xor(t0, 32));
        float t1 = vmB[nt];
        t1 = fmaxf(t1, __shfl_xor(t1, 16));
        t1 = fmaxf(t1, __shfl_xor(t1, 32));
        if (q == 0) out[(size_t)(voxA + 0) * ODIM + nt * 16 + m16] = t0 + b3r[nt];
        if (q == 1) out[(size_t)(voxA + 1) * ODIM + nt * 16 + m16] = t1 + b3r[nt];
    }
}

extern "C" void kernel_launch(void* const* d_in, const int* in_sizes, int n_in,
                              void* d_out, int out_size, void* d_ws, size_t ws_size,
                              hipStream_t stream) {
    const float* vf  = (const float*)d_in[0];
    const int*   vnp = (const int*)d_in[1];
    const float* W1  = (const float*)d_in[2];
    const float* b1  = (const float*)d_in[3];
    const float* g1  = (const float*)d_in[4];
    const float* be1 = (const float*)d_in[5];
    const float* m1  = (const float*)d_in[6];
    const float* v1  = (const float*)d_in[7];
    const float* W2  = (const float*)d_in[8];
    const float* b2  = (const float*)d_in[9];
    const float* g2  = (const float*)d_in[10];
    const float* be2 = (const float*)d_in[11];
    const float* m2  = (const float*)d_in[12];
    const float* v2  = (const float*)d_in[13];
    const float* W3  = (const float*)d_in[14];
    const float* b3  = (const float*)d_in[15];
    float* out = (float*)d_out;

    _Float16* wsh = (_Float16*)d_ws;
    float*    wsf = (float*)((char*)d_ws + WS_F32_BYTE);

    vfe_fold<<<(FOLD_THREADS + 255) / 256, 256, 0, stream>>>(
        W1, b1, g1, be1, m1, v1, W2, b2, g2, be2, m2, v2, W3, b3, wsh, wsf);

    const int blocks = (NVOX * PPTS) / 128;   // 12500
    vfe_mfma<<<blocks, 128, 0, stream>>>(vf, vnp, wsh, wsf, out);
}